// Round 9
// baseline (226.357 us; speedup 1.0000x reference)
//
#include <hip/hip_runtime.h>
#include <math.h>

#define B_TOT 2048
#define IN_TOT 512
#define OUT_TOT 512
#define CPB 8             // cols per block
#define RPB 256           // rows per block (32 ty-slots x M=8)
#define M 8               // rows per thread
#define QH 64             // quads per k-half (256 k)

__global__ __launch_bounds__(512, 4) void morph_kernel(
    const float* __restrict__ x,
    const float* __restrict__ wdil,
    const float* __restrict__ wero,
    float* __restrict__ out)
{
    // weights: [arr][col*128 quads], 8192 floats = 32 KB, staged once.
    // After the post-compute barrier the first 4096 floats are reused as the
    // k-half combine buffer, laid out [value 0..15][thread 0..255].
    __shared__ float w_s[2 * CPB * IN_TOT / 1];  // 8192 floats

    const int tid  = (int)threadIdx.x;
    const int half = tid >> 8;     // k-half: quads [half*64, half*64+64)
    const int t    = tid & 255;
    const int tx   = t & 7;        // col within block
    const int ty   = t >> 3;       // row slot (0..31): rows ty + 32*mi

    const int col0 = (int)blockIdx.x * CPB;
    const int row0 = (int)blockIdx.y * RPB;

    // ---- stage weights once, source-side 3-bit XOR quad swizzle ----
    // phys quad p of col c holds logical quad l = (p & ~7) | ((p ^ c) & 7)
#pragma unroll
    for (int i = 0; i < 2; ++i) {
        const int s  = i * 512 + tid;          // quad slot in [0, 1024)
        const int c  = s >> 7;
        const int qp = s & 127;
        const int ql = (qp & ~7) | ((qp ^ c) & 7);
        const int g  = (col0 + c) * IN_TOT + ql * 4;
        *(float4*)&w_s[s * 4]        = *(const float4*)(wdil + g);
        *(float4*)&w_s[4096 + s * 4] = *(const float4*)(wero + g);
    }
    __syncthreads();

    float dil[M], ero[M];
#pragma unroll
    for (int mi = 0; mi < M; ++mi) { dil[mi] = -INFINITY; ero[mi] = INFINITY; }

    // per-row x bases for this thread's k-half
    const float* xr[M];
#pragma unroll
    for (int mi = 0; mi < M; ++mi)
        xr[mi] = x + (size_t)(row0 + ty + 32 * mi) * IN_TOT + half * (QH * 4);

    const float* __restrict__ wdp = &w_s[tx * 512];         // col region, 128 quads
    const float* __restrict__ wep = &w_s[4096 + tx * 512];

#pragma unroll 1
    for (int g = 0; g < QH / 8; ++g) {
#pragma unroll
        for (int u = 0; u < 8; ++u) {
            const int qq = g * 8 + u;                 // quad within half
            const int q  = half * QH + qq;            // global quad
            const int ph = (q & ~7) | ((q ^ tx) & 7); // swizzled -> conflict-free
            float4 wd4 = *(const float4*)(wdp + ph * 4);
            float4 we4 = *(const float4*)(wep + ph * 4);

            float4 xv[M];
#pragma unroll
            for (int mi = 0; mi < M; ++mi)
                xv[mi] = *(const float4*)(xr[mi] + qq * 4);  // imm-offset loads

#pragma unroll
            for (int mi = 0; mi < M; ++mi) {
                dil[mi] = fmaxf(fmaxf(xv[mi].x + wd4.x, xv[mi].y + wd4.y), dil[mi]);
                dil[mi] = fmaxf(fmaxf(xv[mi].z + wd4.z, xv[mi].w + wd4.w), dil[mi]);
                ero[mi] = fminf(fminf(xv[mi].x - we4.x, xv[mi].y - we4.y), ero[mi]);
                ero[mi] = fminf(fminf(xv[mi].z - we4.z, xv[mi].w - we4.w), ero[mi]);
            }
        }
    }

    // ---- combine the two k-halves (exact: max/min associative) ----
    __syncthreads();               // all weight reads done; reuse w_s
    if (half == 1) {
#pragma unroll
        for (int mi = 0; mi < M; ++mi) {
            w_s[mi * 256 + t]        = dil[mi];   // lane-stride-1: conflict-free
            w_s[2048 + mi * 256 + t] = ero[mi];
        }
    }
    __syncthreads();
    if (half == 0) {
        float* op = out + (size_t)(row0 + ty) * OUT_TOT + col0 + tx;
#pragma unroll
        for (int mi = 0; mi < M; ++mi) {
            float d = fmaxf(dil[mi], w_s[mi * 256 + t]);
            float e = fminf(ero[mi], w_s[2048 + mi * 256 + t]);
            op[(size_t)32 * mi * OUT_TOT] = d + e;
        }
    }
}

extern "C" void kernel_launch(void* const* d_in, const int* in_sizes, int n_in,
                              void* d_out, int out_size, void* d_ws, size_t ws_size,
                              hipStream_t stream)
{
    const float* x  = (const float*)d_in[0];
    const float* wd = (const float*)d_in[1];
    const float* we = (const float*)d_in[2];
    float* out = (float*)d_out;

    dim3 grid(OUT_TOT / CPB, B_TOT / RPB);   // (64, 8) = 512 blocks = 2/CU
    dim3 block(512);                         // 2 k-half groups x 256
    hipLaunchKernelGGL(morph_kernel, grid, block, 0, stream, x, wd, we, out);
}

// Round 10
// 117.466 us; speedup vs baseline: 1.9270x; 1.9270x over previous
//
#include <hip/hip_runtime.h>
#include <math.h>

#define B_TOT 2048
#define IN_TOT 512
#define OUT_TOT 512
#define CPB 8             // cols per block
#define RPB 128           // rows per block (32 ty-slots x M=4)
#define M 4               // rows per thread
#define NQ 128            // k-quads

__global__ __launch_bounds__(256, 2) void morph_kernel(
    const float* __restrict__ x,
    const float* __restrict__ wdil,
    const float* __restrict__ wero,
    float* __restrict__ out)
{
    // [arr][col*512 + phys_quad*4 + e] : 2 * 8 cols * 512 k * 4B = 32 KB
    __shared__ float w_s[2 * CPB * IN_TOT];

    const int tid = (int)threadIdx.x;
    const int tx  = tid & 7;      // col within block
    const int ty  = tid >> 3;     // row slot (0..31): rows ty + 32*mi

    const int col0 = (int)blockIdx.x * CPB;
    const int row0 = (int)blockIdx.y * RPB;

    // ---- stage weights once, source-side 3-bit XOR quad swizzle (R6-proven) ----
#pragma unroll
    for (int i = 0; i < 4; ++i) {
        const int s  = i * 256 + tid;           // quad slot in [0, 1024)
        const int c  = s >> 7;
        const int qp = s & 127;
        const int ql = (qp & ~7) | ((qp ^ c) & 7);
        const int g  = (col0 + c) * IN_TOT + ql * 4;
        *(float4*)&w_s[s * 4]        = *(const float4*)(wdil + g);
        *(float4*)&w_s[4096 + s * 4] = *(const float4*)(wero + g);
    }
    __syncthreads();   // the only barrier

    float dil[M], ero[M];
#pragma unroll
    for (int mi = 0; mi < M; ++mi) { dil[mi] = -INFINITY; ero[mi] = INFINITY; }

    const float* xr0 = x + (size_t)(row0 + ty) * IN_TOT;
    const float* xr1 = xr0 + (size_t)32 * IN_TOT;
    const float* xr2 = xr0 + (size_t)64 * IN_TOT;
    const float* xr3 = xr0 + (size_t)96 * IN_TOT;

    const float* __restrict__ wdp = &w_s[tx * 512];
    const float* __restrict__ wep = &w_s[4096 + tx * 512];

#define XISSUE(b, qq) do { const int _o = (qq) * 4;          \
        b[0] = *(const float4*)(xr0 + _o);                   \
        b[1] = *(const float4*)(xr1 + _o);                   \
        b[2] = *(const float4*)(xr2 + _o);                   \
        b[3] = *(const float4*)(xr3 + _o); } while (0)

#define WISSUE(wdv, wev, qq) do {                            \
        const int _p = ((((qq) & ~7) | (((qq) ^ tx) & 7)) << 2); \
        wdv = *(const float4*)(wdp + _p);                    \
        wev = *(const float4*)(wep + _p); } while (0)

#define COMPUTE(xb, wd4, we4) do {                           \
        _Pragma("unroll")                                    \
        for (int mi = 0; mi < M; ++mi) {                     \
            dil[mi] = fmaxf(fmaxf(xb[mi].x + wd4.x, xb[mi].y + wd4.y), dil[mi]); \
            dil[mi] = fmaxf(fmaxf(xb[mi].z + wd4.z, xb[mi].w + wd4.w), dil[mi]); \
            ero[mi] = fminf(fminf(xb[mi].x - we4.x, xb[mi].y - we4.y), ero[mi]); \
            ero[mi] = fminf(fminf(xb[mi].z - we4.z, xb[mi].w - we4.w), ero[mi]); \
        } } while (0)

    float4 x0[M], x1[M], x2[M], x3[M];
    float4 wd0, we0, wd1, we1, wd2, we2, wd3, we3;

    // prologue: fill the 4-deep pipeline
    XISSUE(x0, 0); XISSUE(x1, 1); XISSUE(x2, 2); XISSUE(x3, 3);
    WISSUE(wd0, we0, 0); WISSUE(wd1, we1, 1);
    WISSUE(wd2, we2, 2); WISSUE(wd3, we3, 3);

#pragma unroll 1
    for (int q = 0; q < NQ; q += 4) {
        int qn = q + 4; if (qn > NQ - 4) qn = NQ - 4;   // uniform clamp, branch-free

        COMPUTE(x0, wd0, we0);
        XISSUE(x0, qn);     WISSUE(wd0, we0, qn);

        COMPUTE(x1, wd1, we1);
        XISSUE(x1, qn + 1); WISSUE(wd1, we1, qn + 1);

        COMPUTE(x2, wd2, we2);
        XISSUE(x2, qn + 2); WISSUE(wd2, we2, qn + 2);

        COMPUTE(x3, wd3, we3);
        XISSUE(x3, qn + 3); WISSUE(wd3, we3, qn + 3);
    }
#undef XISSUE
#undef WISSUE
#undef COMPUTE

    float* op = out + (size_t)(row0 + ty) * OUT_TOT + col0 + tx;
#pragma unroll
    for (int mi = 0; mi < M; ++mi)
        op[(size_t)32 * mi * OUT_TOT] = dil[mi] + ero[mi];
}

extern "C" void kernel_launch(void* const* d_in, const int* in_sizes, int n_in,
                              void* d_out, int out_size, void* d_ws, size_t ws_size,
                              hipStream_t stream)
{
    const float* x  = (const float*)d_in[0];
    const float* wd = (const float*)d_in[1];
    const float* we = (const float*)d_in[2];
    float* out = (float*)d_out;

    dim3 grid(OUT_TOT / CPB, B_TOT / RPB);   // (64, 16) = 1024 blocks = 4/CU
    dim3 block(256);
    hipLaunchKernelGGL(morph_kernel, grid, block, 0, stream, x, wd, we, out);
}

// Round 11
// 74.202 us; speedup vs baseline: 3.0505x; 1.5831x over previous
//
#include <hip/hip_runtime.h>
#include <math.h>

#define B_TOT 2048
#define IN_TOT 512
#define OUT_TOT 512
#define CPB 8             // cols per block
#define RPB 256           // rows per block (32 ty-slots x M=8)
#define M 8               // rows per thread
#define QH 64             // quads per k-half (256 k)

__global__ __launch_bounds__(512, 2) void morph_kernel(
    const float* __restrict__ x,
    const float* __restrict__ wdil,
    const float* __restrict__ wero,
    float* __restrict__ out)
{
    // weights: wd in [0,4096), we in [4096,8192) floats = 32 KB, staged once.
    // reused as the k-half combine buffer after the post-compute barrier.
    __shared__ float w_s[8192];

    const int tid  = (int)threadIdx.x;
    const int half = tid >> 8;     // k-half: quads [half*64, half*64+64)
    const int t    = tid & 255;
    const int tx   = t & 7;        // col within block
    const int ty   = t >> 3;       // row slot (0..31): rows ty + 32*mi

    const int col0 = (int)blockIdx.x * CPB;
    const int row0 = (int)blockIdx.y * RPB;

    // ---- stage weights once, source-side 3-bit XOR quad swizzle (R6-proven) ----
    // phys quad p of col c holds logical quad l = (p & ~7) | ((p ^ c) & 7)
#pragma unroll
    for (int i = 0; i < 2; ++i) {
        const int s  = i * 512 + tid;          // quad slot in [0, 1024)
        const int c  = s >> 7;
        const int qp = s & 127;
        const int ql = (qp & ~7) | ((qp ^ c) & 7);
        const int g  = (col0 + c) * IN_TOT + ql * 4;
        *(float4*)&w_s[s * 4]        = *(const float4*)(wdil + g);
        *(float4*)&w_s[4096 + s * 4] = *(const float4*)(wero + g);
    }
    __syncthreads();

    float dil[M], ero[M];
#pragma unroll
    for (int mi = 0; mi < M; ++mi) { dil[mi] = -INFINITY; ero[mi] = INFINITY; }

    // per-row x bases for this thread's k-half; all inner loads use imm offsets
    const float* xr[M];
#pragma unroll
    for (int mi = 0; mi < M; ++mi)
        xr[mi] = x + (size_t)(row0 + ty + 32 * mi) * IN_TOT + half * (QH * 4);

    // 8 precomputed swizzled weight pointers; 'half' folded in so the group
    // offset (g*8 quads = 128B) is a compile-time ds_read immediate.
    const float* wq[8];
#pragma unroll
    for (int j = 0; j < 8; ++j)
        wq[j] = &w_s[tx * 512 + half * 256 + ((j ^ tx) & 7) * 4];

#pragma unroll 1
    for (int g = 0; g < QH / 8; ++g) {
#pragma unroll
        for (int u = 0; u < 8; ++u) {
            const int qq = g * 8 + u;                 // quad within half
            float4 wd4 = *(const float4*)(wq[u] + g * 32);          // imm offset
            float4 we4 = *(const float4*)(wq[u] + 4096 + g * 32);   // +16KB imm

            float4 xv[M];
#pragma unroll
            for (int mi = 0; mi < M; ++mi)
                xv[mi] = *(const float4*)(xr[mi] + qq * 4);  // imm-offset loads

#pragma unroll
            for (int mi = 0; mi < M; ++mi) {
                dil[mi] = fmaxf(fmaxf(xv[mi].x + wd4.x, xv[mi].y + wd4.y), dil[mi]);
                dil[mi] = fmaxf(fmaxf(xv[mi].z + wd4.z, xv[mi].w + wd4.w), dil[mi]);
                ero[mi] = fminf(fminf(xv[mi].x - we4.x, xv[mi].y - we4.y), ero[mi]);
                ero[mi] = fminf(fminf(xv[mi].z - we4.z, xv[mi].w - we4.w), ero[mi]);
            }
        }
    }

    // ---- combine the two k-halves (exact: max/min associative) ----
    __syncthreads();               // all weight reads done; reuse w_s
    if (half == 1) {
#pragma unroll
        for (int mi = 0; mi < M; ++mi) {
            w_s[mi * 256 + t]        = dil[mi];   // lane-stride-1: conflict-free
            w_s[2048 + mi * 256 + t] = ero[mi];
        }
    }
    __syncthreads();
    if (half == 0) {
        float* op = out + (size_t)(row0 + ty) * OUT_TOT + col0 + tx;
#pragma unroll
        for (int mi = 0; mi < M; ++mi) {
            float d = fmaxf(dil[mi], w_s[mi * 256 + t]);
            float e = fminf(ero[mi], w_s[2048 + mi * 256 + t]);
            op[(size_t)32 * mi * OUT_TOT] = d + e;
        }
    }
}

extern "C" void kernel_launch(void* const* d_in, const int* in_sizes, int n_in,
                              void* d_out, int out_size, void* d_ws, size_t ws_size,
                              hipStream_t stream)
{
    const float* x  = (const float*)d_in[0];
    const float* wd = (const float*)d_in[1];
    const float* we = (const float*)d_in[2];
    float* out = (float*)d_out;

    dim3 grid(OUT_TOT / CPB, B_TOT / RPB);   // (64, 8) = 512 blocks = 2/CU
    dim3 block(512);                         // 2 k-half groups x 256
    hipLaunchKernelGGL(morph_kernel, grid, block, 0, stream, x, wd, we, out);
}

// Round 12
// 73.728 us; speedup vs baseline: 3.0702x; 1.0064x over previous
//
#include <hip/hip_runtime.h>
#include <math.h>

#define B_TOT 2048
#define IN_TOT 512
#define OUT_TOT 512
#define CPB 8             // cols per block
#define RPB 256           // rows per block (32 ty-slots x M=8)
#define M 8               // rows per thread
#define QH 64             // quads per k-half (256 k)

__global__ __launch_bounds__(512, 2) void morph_kernel(
    const float* __restrict__ x,
    const float* __restrict__ wdil,
    const float* __restrict__ wero,
    float* __restrict__ out)
{
    // weights: wd in [0,4096), we in [4096,8192) floats = 32 KB, staged once.
    // reused as the k-half combine buffer after the post-compute barrier.
    __shared__ float w_s[8192];

    const int tid  = (int)threadIdx.x;
    const int half = tid >> 8;     // k-half: quads [half*64, half*64+64)
    const int t    = tid & 255;
    const int tx   = t & 7;        // col within block
    const int ty   = t >> 3;       // row slot (0..31): rows ty + 32*mi

    const int col0 = (int)blockIdx.x * CPB;
    const int row0 = (int)blockIdx.y * RPB;

    // ---- stage weights once, source-side 3-bit XOR quad swizzle (R6-proven) ----
    // phys quad p of col c holds logical quad l = (p & ~7) | ((p ^ c) & 7)
#pragma unroll
    for (int i = 0; i < 2; ++i) {
        const int s  = i * 512 + tid;          // quad slot in [0, 1024)
        const int c  = s >> 7;
        const int qp = s & 127;
        const int ql = (qp & ~7) | ((qp ^ c) & 7);
        const int g  = (col0 + c) * IN_TOT + ql * 4;
        *(float4*)&w_s[s * 4]        = *(const float4*)(wdil + g);
        *(float4*)&w_s[4096 + s * 4] = *(const float4*)(wero + g);
    }
    __syncthreads();

    float dil[M], ero[M];
#pragma unroll
    for (int mi = 0; mi < M; ++mi) { dil[mi] = -INFINITY; ero[mi] = INFINITY; }

    // per-row x bases for this thread's k-half; all inner loads use imm offsets
    const float* xr[M];
#pragma unroll
    for (int mi = 0; mi < M; ++mi)
        xr[mi] = x + (size_t)(row0 + ty + 32 * mi) * IN_TOT + half * (QH * 4);

    // 8 precomputed swizzled weight pointers; 'half' folded in so the group
    // offset (g*8 quads = 128B) is a compile-time ds_read immediate.
    const float* wq[8];
#pragma unroll
    for (int j = 0; j < 8; ++j)
        wq[j] = &w_s[tx * 512 + half * 256 + ((j ^ tx) & 7) * 4];

#pragma unroll 1
    for (int g = 0; g < QH / 8; ++g) {
#pragma unroll
        for (int u = 0; u < 8; ++u) {
            const int qq = g * 8 + u;                 // quad within half
            float4 wd4 = *(const float4*)(wq[u] + g * 32);          // imm offset
            float4 we4 = *(const float4*)(wq[u] + 4096 + g * 32);   // +16KB imm

            float4 xv[M];
#pragma unroll
            for (int mi = 0; mi < M; ++mi)
                xv[mi] = *(const float4*)(xr[mi] + qq * 4);  // imm-offset loads

#pragma unroll
            for (int mi = 0; mi < M; ++mi) {
                dil[mi] = fmaxf(fmaxf(xv[mi].x + wd4.x, xv[mi].y + wd4.y), dil[mi]);
                dil[mi] = fmaxf(fmaxf(xv[mi].z + wd4.z, xv[mi].w + wd4.w), dil[mi]);
                ero[mi] = fminf(fminf(xv[mi].x - we4.x, xv[mi].y - we4.y), ero[mi]);
                ero[mi] = fminf(fminf(xv[mi].z - we4.z, xv[mi].w - we4.w), ero[mi]);
            }
        }
    }

    // ---- combine the two k-halves (exact: max/min associative) ----
    __syncthreads();               // all weight reads done; reuse w_s
    if (half == 1) {
#pragma unroll
        for (int mi = 0; mi < M; ++mi) {
            w_s[mi * 256 + t]        = dil[mi];   // lane-stride-1: conflict-free
            w_s[2048 + mi * 256 + t] = ero[mi];
        }
    }
    __syncthreads();
    if (half == 0) {
        float* op = out + (size_t)(row0 + ty) * OUT_TOT + col0 + tx;
#pragma unroll
        for (int mi = 0; mi < M; ++mi) {
            float d = fmaxf(dil[mi], w_s[mi * 256 + t]);
            float e = fminf(ero[mi], w_s[2048 + mi * 256 + t]);
            op[(size_t)32 * mi * OUT_TOT] = d + e;
        }
    }
}

extern "C" void kernel_launch(void* const* d_in, const int* in_sizes, int n_in,
                              void* d_out, int out_size, void* d_ws, size_t ws_size,
                              hipStream_t stream)
{
    const float* x  = (const float*)d_in[0];
    const float* wd = (const float*)d_in[1];
    const float* we = (const float*)d_in[2];
    float* out = (float*)d_out;

    dim3 grid(OUT_TOT / CPB, B_TOT / RPB);   // (64, 8) = 512 blocks = 2/CU
    dim3 block(512);                         // 2 k-half groups x 256
    hipLaunchKernelGGL(morph_kernel, grid, block, 0, stream, x, wd, we, out);
}